// Round 2
// baseline (193.896 us; speedup 1.0000x reference)
//
#include <hip/hip_runtime.h>

// ColorHistogramLoss: soft histogram (Gaussian kernel, 64 bins) over
// pred/target (4,3,256,256) fp32, normalized, cumsum, mean |cdf diff|.
//
// v3: truncated-Gaussian (±8 bins) + ratio-recurrence, scattered into
//   LANE-PAIR-private LDS histogram columns (h[wave][80][32], lane l owns
//   col l>>1). Collision-free ds_add_f32: bank = col%32 -> 2 lanes/bank
//   (free); same-address only when paired lanes share a pixel bin (~1/64).
//   v2's per-WAVE shared hist serialized ~17 lanes/dword per tap -> 136us.
//
// Structure:
//   zero_ws     : zero 24*64-float histogram scratch in d_ws
//   hist_kernel : 768 blocks x 256 thr; pair-private LDS hist columns,
//                 bank-staggered column reduce, global atomics
//   final_kernel: 1 block x 768 thr (12 waves); per-wave scan -> cdf ->
//                 |diff| -> mean scalar to d_out[0]

#define BINS 64
#define NCH 12            // B*C = 4*3
#define HW 65536          // 256*256
#define BPC 32            // pixel-chunks (blocks) per channel-image
#define PIX_PER_BLOCK (HW / BPC)              // 2048
#define THREADS 256
#define R 8               // Gaussian support radius in bins (w <= e^-32 beyond)
#define WIN (2 * R + 1)   // 17 taps
#define PADBINS (BINS + 2 * R)   // 80: pad absorbs edge windows, branch-free
#define NWAVES (THREADS / 64)    // 4
#define COLS 32           // one column per lane pair

__device__ __forceinline__ float fast_exp2(float x) {
#if __has_builtin(__builtin_amdgcn_exp2f)
    return __builtin_amdgcn_exp2f(x);   // v_exp_f32
#else
    return exp2f(x);
#endif
}

__global__ void zero_ws(float* ws, int n) {
    int i = blockIdx.x * blockDim.x + threadIdx.x;
    if (i < n) ws[i] = 0.0f;
}

// weight for bin j: exp(-d^2/2), d = x*64 - (j+0.5) = (i+f) - j, sigma = 1 bin.
//   P_0 = exp(-f^2/2 - R*f)  (one exp2)    B = exp(f)  (one exp2)
//   w_t = CK[t] * P_t ;  P_{t+1} = P_t * B    (t = 0..16, bin = i + t - R)
// CK[t] = exp(-(t-R)^2/2) are compile-time literals.
__global__ __launch_bounds__(THREADS) void hist_kernel(
        const float* __restrict__ pred,
        const float* __restrict__ target,
        float* __restrict__ hist) {
    constexpr float CK[WIN] = {
        1.2664165549094176e-14f, 2.2897348456455526e-11f, 1.5229979744712628e-08f,
        3.7266531720786709e-06f, 3.3546262790251185e-04f, 1.1108996538242306e-02f,
        1.3533528323661270e-01f, 6.0653065971263342e-01f, 1.0f,
        6.0653065971263342e-01f, 1.3533528323661270e-01f, 1.1108996538242306e-02f,
        3.3546262790251185e-04f, 3.7266531720786709e-06f, 1.5229979744712628e-08f,
        2.2897348456455526e-11f, 1.2664165549094176e-14f };

    const int blk   = blockIdx.x;
    const int ch    = blk / BPC;        // 0..23 (0..11 pred, 12..23 target)
    const int chunk = blk % BPC;
    const float* src = (ch < NCH) ? (pred + (size_t)ch * HW)
                                  : (target + (size_t)(ch - NCH) * HW);

    // pair-private padded histogram columns: no wave-level address collisions.
    __shared__ float h[NWAVES][PADBINS][COLS];   // 40960 B
    __shared__ float part[NWAVES][BINS];         // 3072 B

    // zero h (float4-vectorized: 2560 float4s / 256 thr = 10 each)
    float4* hz = (float4*)&h[0][0][0];
    for (int t = threadIdx.x; t < NWAVES * PADBINS * COLS / 4; t += THREADS)
        hz[t] = make_float4(0.f, 0.f, 0.f, 0.f);
    __syncthreads();

    const int wv   = threadIdx.x >> 6;
    const int lane = threadIdx.x & 63;
    float* hcol = &h[wv][0][lane >> 1];   // this pair's column base

    // 512 float4 per block; thread t loads f4[t] and f4[t+256] (coalesced).
    const float4* src4 = (const float4*)(src + chunk * PIX_PER_BLOCK);
    float4 a = src4[threadIdx.x];
    float4 b = src4[threadIdx.x + THREADS];
    float px[8] = {a.x, a.y, a.z, a.w, b.x, b.y, b.z, b.w};  // static-indexed

    const float L = 1.4426950408889634f;   // log2(e)

    #pragma unroll
    for (int p = 0; p < 8; ++p) {
        float xt = px[p] * 64.0f - 0.5f;       // bin-center units, [-0.5, 63.5)
        float fi = rintf(xt);
        fi = fminf(fmaxf(fi, 0.0f), 63.0f);    // defensive clamp
        float f  = xt - fi;                    // [-0.5, 0.5]
        int   i  = (int)fi;                    // nearest bin, 0..63
        float P  = fast_exp2(-(0.5f * L) * (f * f + (float)(2 * R) * f));
        float B  = fast_exp2(L * f);
        float* hp = hcol + i * COLS;           // rows i..i+16 = bins i-R..i+R
        #pragma unroll
        for (int t = 0; t < WIN; ++t) {
            atomicAdd(&hp[t * COLS], CK[t] * P);   // ds_add_f32 offset:t*128
            P *= B;
        }
    }

    __syncthreads();

    // Reduce: wave wv's lane j sums its wave's 32 columns of bin j.
    // Column order staggered by j -> bank (j+c)%32: 2 lanes/bank, free.
    {
        const int j = lane;
        float s = 0.0f;
        #pragma unroll
        for (int c = 0; c < COLS; ++c)
            s += h[wv][R + j][(j + c) & (COLS - 1)];
        part[wv][j] = s;
    }
    __syncthreads();
    if (threadIdx.x < BINS) {
        const int j = threadIdx.x;
        float s = part[0][j] + part[1][j] + part[2][j] + part[3][j];
        atomicAdd(&hist[ch * BINS + j], s);
    }
}

__global__ __launch_bounds__(NCH * 64) void final_kernel(
        const float* __restrict__ hist, float* __restrict__ out) {
    const int w    = threadIdx.x >> 6;   // 0..11 -> (b,c) channel
    const int lane = threadIdx.x & 63;   // bin

    float ph = hist[w * BINS + lane];
    float th = hist[(NCH + w) * BINS + lane];

    // inclusive scan over bins (wave64 shfl_up)
    float ps = ph, ts = th;
    #pragma unroll
    for (int d = 1; d < 64; d <<= 1) {
        float a = __shfl_up(ps, d, 64);
        float b = __shfl_up(ts, d, 64);
        if (lane >= d) { ps += a; ts += b; }
    }
    float ptot = __shfl(ps, 63, 64);
    float ttot = __shfl(ts, 63, 64);
    float pc = ps / (ptot + 1e-8f);
    float tc = ts / (ttot + 1e-8f);
    float dv = fabsf(pc - tc);

    // wave reduce
    #pragma unroll
    for (int k = 32; k >= 1; k >>= 1) dv += __shfl_xor(dv, k, 64);

    __shared__ float warr[NCH];
    if (lane == 0) warr[w] = dv;
    __syncthreads();
    if (threadIdx.x == 0) {
        float s = 0.0f;
        #pragma unroll
        for (int i = 0; i < NCH; ++i) s += warr[i];
        out[0] = s / (float)(NCH * BINS);
    }
}

extern "C" void kernel_launch(void* const* d_in, const int* in_sizes, int n_in,
                              void* d_out, int out_size, void* d_ws, size_t ws_size,
                              hipStream_t stream) {
    const float* pred   = (const float*)d_in[0];
    const float* target = (const float*)d_in[1];
    float* hist = (float*)d_ws;          // 2*NCH*BINS = 1536 floats
    float* out  = (float*)d_out;

    zero_ws<<<dim3((2 * NCH * BINS + 255) / 256), dim3(256), 0, stream>>>(
        hist, 2 * NCH * BINS);
    hist_kernel<<<dim3(2 * NCH * BPC), dim3(THREADS), 0, stream>>>(
        pred, target, hist);
    final_kernel<<<dim3(1), dim3(NCH * 64), 0, stream>>>(hist, out);
}

// Round 3
// 65.421 us; speedup vs baseline: 2.9638x; 2.9638x over previous
//
#include <hip/hip_runtime.h>

// ColorHistogramLoss: soft histogram (Gaussian kernel, 64 bins) over
// pred/target (4,3,256,256) fp32, normalized, cumsum, mean |cdf diff|.
//
// v4: truncated-Gaussian (±6 bins) + ratio-recurrence, LANE-private LDS
//   histogram columns with plain ds_read/ds_write RMW — NO LDS atomics.
//   v2/v3 post-mortem: LDS atomicAdd cost ~200cy/op regardless of
//   contention (v2 pair-collisions == v3 collision-free == 137us, VALU
//   idle) -> the atomic path itself (flat-aperture / safe-FP loop) was
//   the bottleneck, not addressing. Plain ds RMW on lane-private columns
//   needs no atomicity and runs at ~6cy/op.
//
// Structure:
//   hist_kernel : 768 blocks x 128 thr (2 waves); h[wave][76][64] lane
//                 columns, bank-staggered column reduce, plain global
//                 store of per-block 64-bin partial into d_ws slot
//   final_kernel: 1 block x 768 thr (12 waves); sum 32 chunk partials
//                 (coalesced), wave scan -> cdf -> |diff| -> mean
//   (no zero_ws, no atomics anywhere)

#define BINS 64
#define NCH 12            // B*C = 4*3
#define HW 65536          // 256*256
#define BPC 32            // pixel-chunks (blocks) per channel-image
#define PIX_PER_BLOCK (HW / BPC)              // 2048
#define THREADS 128
#define PPT (PIX_PER_BLOCK / THREADS)         // 16 pixels per thread
#define R 6               // Gaussian support radius (edge weight e^-18)
#define WIN (2 * R + 1)   // 13 taps
#define PADBINS (BINS + 2 * R)   // 76: pad absorbs edge windows
#define NW (THREADS / 64)        // 2 waves

__device__ __forceinline__ float fast_exp2(float x) {
#if __has_builtin(__builtin_amdgcn_exp2f)
    return __builtin_amdgcn_exp2f(x);   // v_exp_f32
#else
    return exp2f(x);
#endif
}

// weight for bin j=i+k: exp(-(f-k)^2/2) = CK[t]*P_t, t=k+R,
//   P_0 = exp(-f^2/2 - R*f)  (one exp2)    B = exp(f)  (one exp2)
//   P_{t+1} = P_t * B ;  CK[t] = exp(-(t-R)^2/2)  (compile-time)
__global__ __launch_bounds__(THREADS) void hist_kernel(
        const float* __restrict__ pred,
        const float* __restrict__ target,
        float* __restrict__ part_out) {
    constexpr float CK[WIN] = {
        1.5229979744712628e-08f, 3.7266531720786709e-06f,
        3.3546262790251185e-04f, 1.1108996538242306e-02f,
        1.3533528323661270e-01f, 6.0653065971263342e-01f, 1.0f,
        6.0653065971263342e-01f, 1.3533528323661270e-01f,
        1.1108996538242306e-02f, 3.3546262790251185e-04f,
        3.7266531720786709e-06f, 1.5229979744712628e-08f };

    const int blk   = blockIdx.x;
    const int ch    = blk / BPC;        // 0..23 (0..11 pred, 12..23 target)
    const int chunk = blk % BPC;
    const float* src = (ch < NCH) ? (pred + (size_t)ch * HW)
                                  : (target + (size_t)(ch - NCH) * HW);

    // lane-private padded histogram columns: no atomicity needed at all.
    __shared__ float h[NW][PADBINS][64];   // 38912 B
    __shared__ float part[NW][BINS];

    const int wv   = threadIdx.x >> 6;
    const int lane = threadIdx.x & 63;

    // zero h: 9728 floats / 128 thr = 76 each, as float4 (2432 f4 / 128 = 19)
    {
        float4* hz = (float4*)&h[0][0][0];
        #pragma unroll
        for (int t = 0; t < NW * PADBINS * 64 / 4 / THREADS; ++t)
            hz[threadIdx.x + t * THREADS] = make_float4(0.f, 0.f, 0.f, 0.f);
    }
    __syncthreads();

    // 512 float4 per block; thread t loads f4[t + k*128], k=0..3 (coalesced).
    const float4* src4 = (const float4*)(src + chunk * PIX_PER_BLOCK);
    float4 a = src4[threadIdx.x];
    float4 b = src4[threadIdx.x + THREADS];
    float4 c = src4[threadIdx.x + 2 * THREADS];
    float4 d = src4[threadIdx.x + 3 * THREADS];
    float px[PPT] = {a.x, a.y, a.z, a.w, b.x, b.y, b.z, b.w,
                     c.x, c.y, c.z, c.w, d.x, d.y, d.z, d.w};

    const float L = 1.4426950408889634f;   // log2(e)

    #pragma unroll
    for (int p = 0; p < PPT; ++p) {
        float xt = px[p] * 64.0f - 0.5f;       // bin-center units, [-0.5, 63.5)
        float fi = rintf(xt);
        fi = fminf(fmaxf(fi, 0.0f), 63.0f);    // defensive clamp
        float f  = xt - fi;                    // [-0.5, 0.5]
        int   i  = (int)fi;                    // nearest bin, 0..63
        float P  = fast_exp2(-(0.5f * L) * (f * f + (float)(2 * R) * f));
        float B  = fast_exp2(L * f);
        // padded rows i..i+2R = bins i-R..i+R; direct shared indexing ->
        // guaranteed ds_read_b32/ds_write_b32 with offset:t*256 immediates.
        #pragma unroll
        for (int t = 0; t < WIN; ++t) {
            h[wv][i + t][lane] += CK[t] * P;
            P *= B;
        }
    }

    __syncthreads();

    // Per-wave column reduce: lane j sums its wave's 64 columns of bin j.
    // Stagger (j+c)&63 -> 2 lanes/bank, free.
    {
        const int j = lane;
        float s = 0.0f;
        #pragma unroll
        for (int cc = 0; cc < 64; ++cc)
            s += h[wv][R + j][(j + cc) & 63];
        part[wv][j] = s;
    }
    __syncthreads();
    if (threadIdx.x < BINS) {
        const int j = threadIdx.x;
        part_out[blk * BINS + j] = part[0][j] + part[1][j];  // plain store
    }
}

__global__ __launch_bounds__(NCH * 64) void final_kernel(
        const float* __restrict__ part, float* __restrict__ out) {
    const int w    = threadIdx.x >> 6;   // 0..11 -> (b,c) channel
    const int lane = threadIdx.x & 63;   // bin

    // sum the 32 chunk-partials for pred and target (coalesced per c).
    float ph = 0.0f, th = 0.0f;
    #pragma unroll
    for (int c = 0; c < BPC; ++c) {
        ph += part[(w * BPC + c) * BINS + lane];
        th += part[((NCH + w) * BPC + c) * BINS + lane];
    }

    // inclusive scan over bins (wave64 shfl_up)
    float ps = ph, ts = th;
    #pragma unroll
    for (int d = 1; d < 64; d <<= 1) {
        float a = __shfl_up(ps, d, 64);
        float b = __shfl_up(ts, d, 64);
        if (lane >= d) { ps += a; ts += b; }
    }
    float ptot = __shfl(ps, 63, 64);
    float ttot = __shfl(ts, 63, 64);
    float pc = ps / (ptot + 1e-8f);
    float tc = ts / (ttot + 1e-8f);
    float dv = fabsf(pc - tc);

    // wave reduce
    #pragma unroll
    for (int k = 32; k >= 1; k >>= 1) dv += __shfl_xor(dv, k, 64);

    __shared__ float warr[NCH];
    if (lane == 0) warr[w] = dv;
    __syncthreads();
    if (threadIdx.x == 0) {
        float s = 0.0f;
        #pragma unroll
        for (int i = 0; i < NCH; ++i) s += warr[i];
        out[0] = s / (float)(NCH * BINS);
    }
}

extern "C" void kernel_launch(void* const* d_in, const int* in_sizes, int n_in,
                              void* d_out, int out_size, void* d_ws, size_t ws_size,
                              hipStream_t stream) {
    const float* pred   = (const float*)d_in[0];
    const float* target = (const float*)d_in[1];
    float* part = (float*)d_ws;          // 768*64 floats = 196 KB partials
    float* out  = (float*)d_out;

    hist_kernel<<<dim3(2 * NCH * BPC), dim3(THREADS), 0, stream>>>(
        pred, target, part);
    final_kernel<<<dim3(1), dim3(NCH * 64), 0, stream>>>(part, out);
}